// Round 1
// 294.187 us; speedup vs baseline: 1.0311x; 1.0311x over previous
//
#include <hip/hip_runtime.h>

#define N_THRESH 100
#define NBINS 101    // cnt in [0, 100]
#define TPB 256      // threads per block; each thread owns a private u16 column
#define CHUNK 63     // vec4-iters per thread between flushes: 63*4=252 <= 255 (u8 fields)

// ---------------------------------------------------------------------------
// Kernel 0: zero the 101-entry global accumulator (d_ws poisoned 0xAA per call).
// ---------------------------------------------------------------------------
__global__ void zero_ws_kernel(unsigned long long* __restrict__ ws) {
    int i = threadIdx.x;
    if (i < NBINS) ws[i] = 0ull;
}

// ---------------------------------------------------------------------------
// Branch-free exact bin: cnt = searchsorted(thresholds, v, side='left'),
// thresholds[k] = float32(double(k)*0.01) (bit-exact np.arange match).
// e = trunc(fl(v*100)) is within 1 of the answer, so
// cnt = e + (t_e < v) + (t_{e+1} < v) exactly. All in registers.
// ---------------------------------------------------------------------------
__device__ __forceinline__ int bin_of(float v) {
    int e = (int)(v * 100.0f);
    e = e < 0 ? 0 : (e > 99 ? 99 : e);
    double ed = (double)e * 0.01;
    float t0 = (float)ed;           // threshold e
    float t1 = (float)(ed + 0.01);  // threshold e+1 (==1.0f when e==99)
    int c = e + (t0 < v ? 1 : 0) + (t1 < v ? 1 : 0);
    return c > N_THRESH ? N_THRESH : c;
}

// Per-thread private cell: NO atomics. Cell layout u16 = (pos<<8) | cnt,
// both fields <= 252 per chunk -> no overflow, no cross-field carry.
__device__ __forceinline__ void bump(unsigned short (*h)[TPB], int tid, float v, int g) {
    h[bin_of(v)][tid] += (unsigned short)(1u + (g != 0 ? 256u : 0u));
}

// ---------------------------------------------------------------------------
// Kernel 1: single-pass histogram, atomic-free.
// h[bin][tid]: each thread owns column tid -> plain ds_read_u16/ds_write_b16
// RMW (the previous version's LDS *atomics* serialized per-lane: ~137 cyc per
// wave64 ds_add == 2048 instr/CU * 137 = the whole 117us. Plain LDS ops run
// at ~4-6 cyc/instr.)
// Bank math: dword = bin*128 + tid/2 -> bank = (tid/2)&31: wave64 puts exactly
// 2 lanes/bank (free per m136); lane pairs share a dword only when bins match
// (byte-enable merge, correct).
// LDS 51.7KB/block -> 3 blocks/CU, 12 waves/CU: still ~10x the in-flight
// loads needed to saturate HBM (Little's law: ~9KB/CU needed).
// ---------------------------------------------------------------------------
__global__ __launch_bounds__(TPB) void hist_kernel(
        const float* __restrict__ pred,
        const int* __restrict__ gt,
        unsigned long long* __restrict__ ws,
        int n) {
    __shared__ unsigned short h[NBINS][TPB];   // 51,712 B

    const int tid = threadIdx.x;

    for (int i = tid; i < NBINS * (TPB / 2); i += TPB)   // NBINS*128 dwords
        ((unsigned int*)h)[i] = 0u;
    __syncthreads();

    const int nvec = n >> 2;
    const float4* __restrict__ p4 = (const float4*)pred;
    const int4*   __restrict__ g4 = (const int4*)gt;
    const int gsz = gridDim.x * blockDim.x;
    const int i0  = blockIdx.x * blockDim.x + tid;
    const int iters = (nvec + gsz - 1) / gsz;   // uniform across all threads

    // carried across chunk flushes (only used when n is huge; single chunk here)
    unsigned long long acc_cnt = 0ull, acc_pos = 0ull;

    int it = 0;
    for (;;) {
        const int cap = min(iters, it + CHUNK);   // uniform -> safe syncthreads
        // 4x unrolled: 8 x 16B loads issued per iter before the RMW chain
        for (; it + 4 <= cap; it += 4) {
            const int i = i0 + it * gsz;
            if (i + 3 * gsz < nvec) {
                float4 pa = p4[i];           int4 ga = g4[i];
                float4 pb = p4[i + gsz];     int4 gb = g4[i + gsz];
                float4 pc = p4[i + 2 * gsz]; int4 gc = g4[i + 2 * gsz];
                float4 pd = p4[i + 3 * gsz]; int4 gd = g4[i + 3 * gsz];
                bump(h, tid, pa.x, ga.x); bump(h, tid, pa.y, ga.y);
                bump(h, tid, pa.z, ga.z); bump(h, tid, pa.w, ga.w);
                bump(h, tid, pb.x, gb.x); bump(h, tid, pb.y, gb.y);
                bump(h, tid, pb.z, gb.z); bump(h, tid, pb.w, gb.w);
                bump(h, tid, pc.x, gc.x); bump(h, tid, pc.y, gc.y);
                bump(h, tid, pc.z, gc.z); bump(h, tid, pc.w, gc.w);
                bump(h, tid, pd.x, gd.x); bump(h, tid, pd.y, gd.y);
                bump(h, tid, pd.z, gd.z); bump(h, tid, pd.w, gd.w);
            } else {
                for (int u = 0; u < 4; ++u) {
                    int ii = i + u * gsz;
                    if (ii < nvec) {
                        float4 p = p4[ii]; int4 g = g4[ii];
                        bump(h, tid, p.x, g.x); bump(h, tid, p.y, g.y);
                        bump(h, tid, p.z, g.z); bump(h, tid, p.w, g.w);
                    }
                }
            }
        }
        for (; it < cap; ++it) {
            int i = i0 + it * gsz;
            if (i < nvec) {
                float4 p = p4[i]; int4 g = g4[i];
                bump(h, tid, p.x, g.x); bump(h, tid, p.y, g.y);
                bump(h, tid, p.z, g.z); bump(h, tid, p.w, g.w);
            }
        }
        if (it >= iters) break;

        // mid-chunk flush (never runs for n = 2^25; keeps u8 fields safe for any n)
        __syncthreads();
        if (tid < NBINS) {
            unsigned int c = 0, p = 0;
            const unsigned int* row = (const unsigned int*)&h[tid][0];
            for (int j = 0; j < TPB / 2; ++j) {
                unsigned int v = row[(j + tid) & (TPB / 2 - 1)];  // staggered: 2 lanes/bank
                c += (v & 0xffu) + ((v >> 16) & 0xffu);
                p += ((v >> 8) & 0xffu) + ((v >> 24) & 0xffu);
            }
            acc_cnt += c; acc_pos += p;
        }
        __syncthreads();
        for (int i = tid; i < NBINS * (TPB / 2); i += TPB)
            ((unsigned int*)h)[i] = 0u;
        __syncthreads();
    }

    // tail (n not multiple of 4) — empty for N=2^25; lands in thread 0's column
    if (blockIdx.x == 0 && tid == 0) {
        for (int k = nvec << 2; k < n; ++k) {
            int b = bin_of(pred[k]);
            h[b][0] = (unsigned short)(h[b][0] + (1u + (gt[k] != 0 ? 256u : 0u)));
        }
    }

    __syncthreads();
    // fold: bin tid sums its 256 u16 cells (128 dwords, staggered reads),
    // then ONE global atomic per (block, bin): 768*101 total, negligible.
    if (tid < NBINS) {
        unsigned int c = 0, p = 0;
        const unsigned int* row = (const unsigned int*)&h[tid][0];
        for (int j = 0; j < TPB / 2; ++j) {
            unsigned int v = row[(j + tid) & (TPB / 2 - 1)];
            c += (v & 0xffu) + ((v >> 16) & 0xffu);
            p += ((v >> 8) & 0xffu) + ((v >> 24) & 0xffu);
        }
        unsigned long long cnt = acc_cnt + c;
        unsigned long long pos = acc_pos + p;
        unsigned long long s = (pos << 32) | cnt;
        if (s) atomicAdd(&ws[tid], s);
    }
}

// ---------------------------------------------------------------------------
// Kernel 2: suffix sums + IoU. One block, trivial cost.
// out[0:100] = thresholds, out[100:200] = ious.
// ---------------------------------------------------------------------------
__global__ void finalize_kernel(const unsigned long long* __restrict__ ws,
                                float* __restrict__ out) {
    __shared__ unsigned int pos[NBINS], all[NBINS];
    int k = threadIdx.x;
    if (k < NBINS) {
        unsigned long long h = ws[k];
        pos[k] = (unsigned int)(h >> 32);
        all[k] = (unsigned int)(h & 0xffffffffull);
    }
    __syncthreads();
    if (k < N_THRESH) {
        out[k] = (float)((double)k * 0.01);
        unsigned long long tp = 0, pp = 0, ngt = 0;
        for (int c = k + 1; c <= N_THRESH; ++c) { tp += pos[c]; pp += all[c]; }
        for (int c = 0; c <= N_THRESH; ++c) ngt += pos[c];
        long long uni = (long long)(pp + ngt - tp);   // TP + FP + FN
        double iou = (uni > 0) ? (double)tp / (double)uni : 0.0;
        out[N_THRESH + k] = (float)iou;
    }
}

// ---------------------------------------------------------------------------
extern "C" void kernel_launch(void* const* d_in, const int* in_sizes, int n_in,
                              void* d_out, int out_size, void* d_ws, size_t ws_size,
                              hipStream_t stream) {
    const float* pred = (const float*)d_in[0];
    const int*   gt   = (const int*)d_in[1];
    float* out = (float*)d_out;
    unsigned long long* ws = (unsigned long long*)d_ws;
    int n = in_sizes[0];

    zero_ws_kernel<<<1, 128, 0, stream>>>(ws);
    // 768 blocks x 256 threads: LDS (51.7KB) caps residency at 3 blocks/CU on
    // 256 CUs -> grid == exactly resident set, no second dispatch wave.
    // Per thread: ceil(8.39M/196608)=43 float4 -> max 172 elems/cell (u8-safe).
    hist_kernel<<<768, TPB, 0, stream>>>(pred, gt, ws, n);
    finalize_kernel<<<1, 128, 0, stream>>>(ws, out);
}